// Round 6
// baseline (2018.469 us; speedup 1.0000x reference)
//
#include <hip/hip_runtime.h>
#include <math.h>

#define B_TOT 4096
#define CHUNK 1024

typedef _Float16 half_t;
typedef _Float16 h2 __attribute__((ext_vector_type(2)));

#if __has_builtin(__builtin_amdgcn_fdot2)
#define FDOT2(a, b, c) __builtin_amdgcn_fdot2((a), (b), (c), false)
#else
#define FDOT2(a, b, c) fmaf((float)(a)[1], (float)(b)[1], fmaf((float)(a)[0], (float)(b)[0], (c)))
#endif

// Per-wave LDS: K 49x36 halves (72B rows, fp16), V 49x34 floats (136B rows, fp32).
// Block: 4 waves KV (40768) + wi stage slot (12288) = 53056 B -> 3 blocks/CU.
// FF weights (32 KB) overlay [0,32768) (over KV) after attention, barrier-guarded.
// V stays fp32: fp16 V measured absmax 2.9e-3 > 1.19e-3 threshold (round 4).
#define KSTR 36          // halves per K row
#define VSTR 34          // floats per V row
#define KBYTES (49 * 72)
#define WAVE_LDS (49 * 72 + 49 * 136)  // 10192
#define WI_OFF  (4 * WAVE_LDS)         // 40768
#define BLOCK_LDS (WI_OFF + 12288)     // 53056

// ---------------------------------------------------------------------------
// Fused: patch conv (1->32, k4 s4) + 2 transformer blocks.
// One WAVE per sample, one LANE per token. Activations in registers.
// K fp16 / V fp32 in per-wave LDS; scores via v_dot2_f32_f16.
// qkv in-proj weights AND FF weights staged in LDS (broadcast b128 reads);
// out-proj weights via wave-uniform scalar loads (only 4 KB).
// ---------------------------------------------------------------------------
__global__ __launch_bounds__(256) void k_tokens(
    const float* __restrict__ x, const float* __restrict__ pw, const float* __restrict__ pb,
    const float* __restrict__ ln1g, const float* __restrict__ ln1b,
    const float* __restrict__ wi, const float* __restrict__ bi,
    const float* __restrict__ wo, const float* __restrict__ bo,
    const float* __restrict__ ln2g, const float* __restrict__ ln2b,
    const float* __restrict__ w1, const float* __restrict__ fb1,
    const float* __restrict__ w2t, const float* __restrict__ fb2,
    float* __restrict__ tokens)
{
    __shared__ __align__(16) unsigned char Lraw[BLOCK_LDS];
    const int tid = threadIdx.x;
    const int wv = tid >> 6, lane = tid & 63;
    const int b = blockIdx.x * 4 + wv;
    half_t* Kb = (half_t*)(Lraw + wv * WAVE_LDS);
    float*  Vb = (float*)(Lraw + wv * WAVE_LDS + KBYTES);
    const float* wiL = (const float*)(Lraw + WI_OFF);
    float* Lf = (float*)Lraw;            // FF-weight overlay (block-wide)
    const bool is_tok = lane < 49;
    const int s = is_tok ? lane : 48;
    const int py = s / 7, px = s % 7;

    // --- patch conv: direct float4 loads (rows are 16B-aligned) ---
    float xv[16];
    const float* xb = x + (size_t)b * 784 + py * 112 + px * 4;
    #pragma unroll
    for (int r = 0; r < 4; ++r) {
        float4 vq = *(const float4*)(xb + r * 28);
        xv[4 * r + 0] = vq.x; xv[4 * r + 1] = vq.y;
        xv[4 * r + 2] = vq.z; xv[4 * r + 3] = vq.w;
    }
    float t[32];
    #pragma unroll 4
    for (int c = 0; c < 32; ++c) {
        float a = pb[c];
        const float* wr = pw + c * 16;
        #pragma unroll
        for (int i = 0; i < 16; ++i) a = fmaf(xv[i], wr[i], a);
        t[c] = a;
    }

    for (int blk = 0; blk < 2; ++blk) {
        const float* bib = bi + blk * 96;

        // --- LN1 ---
        float mu = 0.f;
        #pragma unroll
        for (int c = 0; c < 32; ++c) mu += t[c];
        mu *= 0.03125f;
        float var = 0.f;
        #pragma unroll
        for (int c = 0; c < 32; ++c) { float d = t[c] - mu; var = fmaf(d, d, var); }
        float rstd = rsqrtf(var * 0.03125f + 1e-5f);
        float xn[32];
        #pragma unroll
        for (int c = 0; c < 32; ++c)
            xn[c] = (t[c] - mu) * rstd * ln1g[blk * 32 + c] + ln1b[blk * 32 + c];

        __syncthreads();   // (A) prior-phase LDS reads complete before overwrite

        // --- stage qkv in-proj weights (12 KB) into LDS ---
        {
            const float4* srcw = (const float4*)(wi + blk * 3072);
            float4* dstw = (float4*)(Lraw + WI_OFF);
            for (int e = tid; e < 768; e += 256) dstw[e] = srcw[e];
        }
        __syncthreads();   // (A2) wi visible

        // --- K projection -> LDS fp16 (broadcast b128 weight reads) ---
        #pragma unroll 4
        for (int d = 0; d < 32; ++d) {
            const float* wr = wiL + (32 + d) * 32;
            float a0 = bib[32 + d], a1 = 0.f;
            #pragma unroll
            for (int c2 = 0; c2 < 4; ++c2) {
                float4 wq = *(const float4*)&wr[4 * c2];
                a0 = fmaf(xn[4 * c2],     wq.x, a0);
                a0 = fmaf(xn[4 * c2 + 1], wq.y, a0);
                a0 = fmaf(xn[4 * c2 + 2], wq.z, a0);
                a0 = fmaf(xn[4 * c2 + 3], wq.w, a0);
            }
            #pragma unroll
            for (int c2 = 4; c2 < 8; ++c2) {
                float4 wq = *(const float4*)&wr[4 * c2];
                a1 = fmaf(xn[4 * c2],     wq.x, a1);
                a1 = fmaf(xn[4 * c2 + 1], wq.y, a1);
                a1 = fmaf(xn[4 * c2 + 2], wq.z, a1);
                a1 = fmaf(xn[4 * c2 + 3], wq.w, a1);
            }
            if (is_tok) Kb[s * KSTR + d] = (half_t)(a0 + a1);
        }
        // --- V projection -> LDS fp32 ---
        #pragma unroll 4
        for (int d = 0; d < 32; ++d) {
            const float* wr = wiL + (64 + d) * 32;
            float a0 = bib[64 + d], a1 = 0.f;
            #pragma unroll
            for (int c2 = 0; c2 < 4; ++c2) {
                float4 wq = *(const float4*)&wr[4 * c2];
                a0 = fmaf(xn[4 * c2],     wq.x, a0);
                a0 = fmaf(xn[4 * c2 + 1], wq.y, a0);
                a0 = fmaf(xn[4 * c2 + 2], wq.z, a0);
                a0 = fmaf(xn[4 * c2 + 3], wq.w, a0);
            }
            #pragma unroll
            for (int c2 = 4; c2 < 8; ++c2) {
                float4 wq = *(const float4*)&wr[4 * c2];
                a1 = fmaf(xn[4 * c2],     wq.x, a1);
                a1 = fmaf(xn[4 * c2 + 1], wq.y, a1);
                a1 = fmaf(xn[4 * c2 + 2], wq.z, a1);
                a1 = fmaf(xn[4 * c2 + 3], wq.w, a1);
            }
            if (is_tok) Vb[s * VSTR + d] = a0 + a1;
        }
        // --- Q projection (scaled), packed to half2 for fdot2 ---
        float q0[32];
        #pragma unroll 4
        for (int d = 0; d < 32; ++d) {
            const float* wr = wiL + d * 32;
            float a0 = bib[d], a1 = 0.f;
            #pragma unroll
            for (int c2 = 0; c2 < 4; ++c2) {
                float4 wq = *(const float4*)&wr[4 * c2];
                a0 = fmaf(xn[4 * c2],     wq.x, a0);
                a0 = fmaf(xn[4 * c2 + 1], wq.y, a0);
                a0 = fmaf(xn[4 * c2 + 2], wq.z, a0);
                a0 = fmaf(xn[4 * c2 + 3], wq.w, a0);
            }
            #pragma unroll
            for (int c2 = 4; c2 < 8; ++c2) {
                float4 wq = *(const float4*)&wr[4 * c2];
                a1 = fmaf(xn[4 * c2],     wq.x, a1);
                a1 = fmaf(xn[4 * c2 + 1], wq.y, a1);
                a1 = fmaf(xn[4 * c2 + 2], wq.z, a1);
                a1 = fmaf(xn[4 * c2 + 3], wq.w, a1);
            }
            q0[d] = (a0 + a1) * 0.25f;
        }
        h2 qh[16];
        #pragma unroll
        for (int i = 0; i < 16; ++i) {
            h2 hh; hh[0] = (half_t)q0[2 * i]; hh[1] = (half_t)q0[2 * i + 1];
            qh[i] = hh;
        }

        // wave-local fence: own K/V ds_writes visible before broadcast reads
        __asm__ volatile("s_waitcnt lgkmcnt(0)" ::: "memory");

        // --- attention: 2 heads of 16 dims, softmax without running max ---
        float o[32];
        #pragma unroll
        for (int d = 0; d < 32; ++d) o[d] = 0.f;
        float l0 = 0.f, l1 = 0.f;
        union H4 { double qd; h2 p[2]; };
        for (int j = 0; j < 49; ++j) {
            const double* kr = (const double*)(Kb + j * KSTR);
            const float* vr = Vb + j * VSTR;
            H4 u0, u1, u2, u3, w0, w1h, w2h, w3;
            u0.qd = kr[0]; u1.qd = kr[1]; u2.qd = kr[2]; u3.qd = kr[3];
            w0.qd = kr[4]; w1h.qd = kr[5]; w2h.qd = kr[6]; w3.qd = kr[7];
            float s0a = 0.f, s0b = 0.f, s1a = 0.f, s1b = 0.f;
            s0a = FDOT2(u0.p[0], qh[0], s0a); s0a = FDOT2(u0.p[1], qh[1], s0a);
            s0b = FDOT2(u1.p[0], qh[2], s0b); s0b = FDOT2(u1.p[1], qh[3], s0b);
            s0a = FDOT2(u2.p[0], qh[4], s0a); s0a = FDOT2(u2.p[1], qh[5], s0a);
            s0b = FDOT2(u3.p[0], qh[6], s0b); s0b = FDOT2(u3.p[1], qh[7], s0b);
            s1a = FDOT2(w0.p[0], qh[8], s1a); s1a = FDOT2(w0.p[1], qh[9], s1a);
            s1b = FDOT2(w1h.p[0], qh[10], s1b); s1b = FDOT2(w1h.p[1], qh[11], s1b);
            s1a = FDOT2(w2h.p[0], qh[12], s1a); s1a = FDOT2(w2h.p[1], qh[13], s1a);
            s1b = FDOT2(w3.p[0], qh[14], s1b); s1b = FDOT2(w3.p[1], qh[15], s1b);
            float p0 = __expf(s0a + s0b), p1 = __expf(s1a + s1b);
            l0 += p0; l1 += p1;
            #pragma unroll
            for (int i = 0; i < 8; ++i) {
                float2 va = *(const float2*)&vr[2 * i];
                o[2 * i]     = fmaf(p0, va.x, o[2 * i]);
                o[2 * i + 1] = fmaf(p0, va.y, o[2 * i + 1]);
                float2 vc = *(const float2*)&vr[16 + 2 * i];
                o[16 + 2 * i]     = fmaf(p1, vc.x, o[16 + 2 * i]);
                o[16 + 2 * i + 1] = fmaf(p1, vc.y, o[16 + 2 * i + 1]);
            }
        }
        float il0 = 1.f / l0, il1 = 1.f / l1;
        #pragma unroll
        for (int d = 0; d < 16; ++d) { o[d] *= il0; o[16 + d] *= il1; }

        // --- out projection + residual (wave-uniform global weights, 4 KB) ---
        #pragma unroll
        for (int c = 0; c < 32; ++c) {
            const float* wr = wo + blk * 1024 + c * 32;
            float a = bo[blk * 32 + c];
            #pragma unroll
            for (int k2 = 0; k2 < 32; ++k2) a = fmaf(o[k2], wr[k2], a);
            t[c] += a;
        }

        // --- LN2 ---
        mu = 0.f;
        #pragma unroll
        for (int c = 0; c < 32; ++c) mu += t[c];
        mu *= 0.03125f;
        var = 0.f;
        #pragma unroll
        for (int c = 0; c < 32; ++c) { float d = t[c] - mu; var = fmaf(d, d, var); }
        rstd = rsqrtf(var * 0.03125f + 1e-5f);
        #pragma unroll
        for (int c = 0; c < 32; ++c)
            xn[c] = (t[c] - mu) * rstd * ln2g[blk * 32 + c] + ln2b[blk * 32 + c];

        __syncthreads();   // (C) all waves done reading K/V + wi

        // --- stage FF weights into LDS (overlay over KV), float4 copy ---
        {
            const float4* src1 = (const float4*)(w1 + blk * 4096);
            const float4* src2 = (const float4*)(w2t + blk * 4096);
            float4* dst = (float4*)Lraw;
            for (int e = tid; e < 1024; e += 256) dst[e] = src1[e];
            for (int e = tid; e < 1024; e += 256) dst[1024 + e] = src2[e];
        }
        __syncthreads();   // (D) FF weights visible

        // --- FF from LDS: broadcast ds_read_b128 rows ---
        const float* w2L = Lf + 4096;
        #pragma unroll 2
        for (int j = 0; j < 128; ++j) {
            const float* wr = Lf + j * 32;
            float ha = fb1[blk * 128 + j], hb = 0.f;
            #pragma unroll
            for (int c2 = 0; c2 < 4; ++c2) {
                float4 wq = *(const float4*)&wr[4 * c2];
                ha = fmaf(xn[4 * c2],     wq.x, ha);
                ha = fmaf(xn[4 * c2 + 1], wq.y, ha);
                ha = fmaf(xn[4 * c2 + 2], wq.z, ha);
                ha = fmaf(xn[4 * c2 + 3], wq.w, ha);
            }
            #pragma unroll
            for (int c2 = 4; c2 < 8; ++c2) {
                float4 wq = *(const float4*)&wr[4 * c2];
                hb = fmaf(xn[4 * c2],     wq.x, hb);
                hb = fmaf(xn[4 * c2 + 1], wq.y, hb);
                hb = fmaf(xn[4 * c2 + 2], wq.z, hb);
                hb = fmaf(xn[4 * c2 + 3], wq.w, hb);
            }
            float h = ha + hb;
            h = 0.5f * h * (1.f + erff(h * 0.7071067811865476f));
            const float* w2r = w2L + j * 32;
            #pragma unroll
            for (int c2 = 0; c2 < 8; ++c2) {
                float4 wq = *(const float4*)&w2r[4 * c2];
                t[4 * c2]     = fmaf(h, wq.x, t[4 * c2]);
                t[4 * c2 + 1] = fmaf(h, wq.y, t[4 * c2 + 1]);
                t[4 * c2 + 2] = fmaf(h, wq.z, t[4 * c2 + 2]);
                t[4 * c2 + 3] = fmaf(h, wq.w, t[4 * c2 + 3]);
            }
        }
        #pragma unroll
        for (int c = 0; c < 32; ++c) t[c] += fb2[blk * 32 + c];
    }

    if (is_tok) {
        float* op = tokens + (size_t)b * 1568 + s * 32;
        #pragma unroll
        for (int c = 0; c < 32; c += 4) {
            float4 vv = make_float4(t[c], t[c + 1], t[c + 2], t[c + 3]);
            *(float4*)&op[c] = vv;
        }
    }
}

// ---------------------------------------------------------------------------
// C[M,N] = A[M,K] @ B[N,K]^T (+bias, optional ReLU). 128x64 tile, BK=16,
// 8x4 microtile.
// ---------------------------------------------------------------------------
__global__ __launch_bounds__(256) void k_gemm(
    const float* __restrict__ A, const float* __restrict__ Bm,
    const float* __restrict__ bias, float* __restrict__ C,
    int M, int N, int K, int relu)
{
    __shared__ float As[16 * 132];
    __shared__ float Bs[16 * 68];
    const int n0 = blockIdx.x * 64, m0 = blockIdx.y * 128;
    const int tid = threadIdx.x;
    const int tx = tid & 15, ty = tid >> 4;
    const int lr = tid >> 1, lk = (tid & 1) * 8;
    const int br = tid >> 2, bk = (tid & 3) * 4;
    float acc[8][4] = {{0.f}};
    for (int k0 = 0; k0 < K; k0 += 16) {
        float4 av0 = *(const float4*)&A[(size_t)(m0 + lr) * K + k0 + lk];
        float4 av1 = *(const float4*)&A[(size_t)(m0 + lr) * K + k0 + lk + 4];
        float4 bv0 = *(const float4*)&Bm[(size_t)(n0 + br) * K + k0 + bk];
        As[(lk + 0) * 132 + lr] = av0.x;
        As[(lk + 1) * 132 + lr] = av0.y;
        As[(lk + 2) * 132 + lr] = av0.z;
        As[(lk + 3) * 132 + lr] = av0.w;
        As[(lk + 4) * 132 + lr] = av1.x;
        As[(lk + 5) * 132 + lr] = av1.y;
        As[(lk + 6) * 132 + lr] = av1.z;
        As[(lk + 7) * 132 + lr] = av1.w;
        Bs[(bk + 0) * 68 + br] = bv0.x;
        Bs[(bk + 1) * 68 + br] = bv0.y;
        Bs[(bk + 2) * 68 + br] = bv0.z;
        Bs[(bk + 3) * 68 + br] = bv0.w;
        __syncthreads();
        #pragma unroll
        for (int k = 0; k < 16; ++k) {
            float4 a0 = *(const float4*)&As[k * 132 + ty * 8];
            float4 a1 = *(const float4*)&As[k * 132 + ty * 8 + 4];
            float4 bv = *(const float4*)&Bs[k * 68 + tx * 4];
            float a8[8] = {a0.x, a0.y, a0.z, a0.w, a1.x, a1.y, a1.z, a1.w};
            float b4[4] = {bv.x, bv.y, bv.z, bv.w};
            #pragma unroll
            for (int i = 0; i < 8; ++i)
                #pragma unroll
                for (int j = 0; j < 4; ++j)
                    acc[i][j] = fmaf(a8[i], b4[j], acc[i][j]);
        }
        __syncthreads();
    }
    #pragma unroll
    for (int i = 0; i < 8; ++i) {
        int m = m0 + ty * 8 + i;
        #pragma unroll
        for (int j = 0; j < 4; ++j) {
            int n = n0 + tx * 4 + j;
            float v = acc[i][j] + (bias ? bias[n] : 0.f);
            if (relu) v = fmaxf(v, 0.f);
            C[(size_t)m * N + n] = v;
        }
    }
}

// ---------------------------------------------------------------------------
// Fuse dec (linear 256->3136) with convt1 (convT 64->32 k4 s2 p1).
// ---------------------------------------------------------------------------
__global__ __launch_bounds__(256) void k_fuse(
    const float* __restrict__ wt1, const float* __restrict__ upt1_b,
    const float* __restrict__ dec_w, const float* __restrict__ dec_b,
    float* __restrict__ Wf, float* __restrict__ bf)
{
    const int n = blockIdx.x;
    const int k = threadIdx.x;
    const int o = n / 196, p = n % 196, y = p / 14, x = p % 14;
    float acc = 0.f, bacc = 0.f;
    for (int ky = 0; ky < 4; ++ky) {
        int iyn = y + 1 - ky;
        if (iyn < 0 || (iyn & 1)) continue;
        int iy = iyn >> 1;
        if (iy > 6) continue;
        for (int kx = 0; kx < 4; ++kx) {
            int ixn = x + 1 - kx;
            if (ixn < 0 || (ixn & 1)) continue;
            int ix = ixn >> 1;
            if (ix > 6) continue;
            for (int c = 0; c < 64; ++c) {
                float w = wt1[((c * 32 + o) * 4 + ky) * 4 + kx];
                int row = c * 49 + iy * 7 + ix;
                acc  = fmaf(w, dec_w[(size_t)row * 256 + k], acc);
                bacc = fmaf(w, dec_b[row], bacc);
            }
        }
    }
    Wf[(size_t)n * 256 + k] = acc;
    if (k == 0) bf[n] = bacc + upt1_b[o];
}

// ---------------------------------------------------------------------------
__global__ __launch_bounds__(256) void k_mnorm(const float* __restrict__ mem, float* __restrict__ inv_norm)
{
    __shared__ float red[256];
    const int row = blockIdx.x, tid = threadIdx.x;
    float v = mem[(size_t)row * 256 + tid];
    red[tid] = v * v;
    __syncthreads();
    for (int s = 128; s > 0; s >>= 1) {
        if (tid < s) red[tid] += red[tid + s];
        __syncthreads();
    }
    if (tid == 0) inv_norm[row] = 1.f / fmaxf(sqrtf(red[0]), 1e-12f);
}

// ---------------------------------------------------------------------------
__global__ __launch_bounds__(256) void k_memread(
    const float* __restrict__ latent, const float* __restrict__ dots,
    const float* __restrict__ inv_mn, const float* __restrict__ mem,
    float* __restrict__ out)
{
    __shared__ float red[256];
    __shared__ int   redi[256];
    __shared__ float inv_x_s;
    const int b = blockIdx.x, tid = threadIdx.x;
    float lx = latent[(size_t)b * 256 + tid];
    red[tid] = lx * lx;
    __syncthreads();
    for (int s = 128; s > 0; s >>= 1) {
        if (tid < s) red[tid] += red[tid + s];
        __syncthreads();
    }
    if (tid == 0) inv_x_s = 1.f / fmaxf(sqrtf(red[0]), 1e-12f);
    __syncthreads();
    const float inv_x = inv_x_s;

    float vals[16];
    for (int j = 0; j < 16; ++j) {
        int m = tid + j * 256;
        vals[j] = dots[(size_t)b * 4096 + m] * inv_mn[m] * inv_x;
    }
    float tv[10]; int ti[10];
    for (int t = 0; t < 10; ++t) {
        float bv = -1e30f; int bidx = 0x7fffffff;
        for (int j = 0; j < 16; ++j) {
            int m = tid + j * 256;
            float v = vals[j];
            if (v > bv || (v == bv && m < bidx)) { bv = v; bidx = m; }
        }
        red[tid] = bv; redi[tid] = bidx;
        __syncthreads();
        for (int s = 128; s > 0; s >>= 1) {
            if (tid < s) {
                float v2 = red[tid + s]; int i2 = redi[tid + s];
                if (v2 > red[tid] || (v2 == red[tid] && i2 < redi[tid])) { red[tid] = v2; redi[tid] = i2; }
            }
            __syncthreads();
        }
        int sel = redi[0];
        tv[t] = red[0]; ti[t] = sel;
        if ((sel & 255) == tid) vals[sel >> 8] = -1e30f;
        __syncthreads();
    }
    float w[10], wsum = 0.f;
    for (int t = 0; t < 10; ++t) { w[t] = expf(tv[t] - tv[0]); wsum += w[t]; }
    float inv_ws = 1.f / wsum;
    float acc = 0.f;
    for (int t = 0; t < 10; ++t) acc += (w[t] * inv_ws) * mem[(size_t)ti[t] * 256 + tid];
    out[(size_t)b * 256 + tid] = acc;
}

// ---------------------------------------------------------------------------
// Weight repack.
// ---------------------------------------------------------------------------
__global__ __launch_bounds__(256) void k_pack(
    const float* __restrict__ wc1, const float* __restrict__ wt2,
    const float* __restrict__ wc2, const float* __restrict__ w2src,
    float* __restrict__ pk2, float* __restrict__ pk3,
    float* __restrict__ pk4, float* __restrict__ pk5)
{
    int i = blockIdx.x * 256 + threadIdx.x;
    if (i < 9216) {
        int o = i & 31, tap = (i >> 5) % 9, c = i / 288;
        pk2[i] = wc1[(o * 32 + c) * 9 + tap];
    }
    if (i < 8192) {
        int o = i & 15, t = (i >> 4) & 3, q = (i >> 6) & 3, c = i >> 8;
        int wy = t >> 1, wx = t & 1, py = q >> 1, px = q & 1;
        int ky = 3 - py - 2 * wy, kx = 3 - px - 2 * wx;
        pk3[i] = wt2[((c * 16 + o) * 4 + ky) * 4 + kx];
    }
    if (i < 1152) {
        int o = i & 7, tap = (i >> 3) % 9, c = i / 72;
        pk4[i] = wc2[(o * 16 + c) * 9 + tap];
    }
    if (i < 8192) {
        int c = i & 31, j = (i >> 5) & 127, bq = i >> 12;
        pk5[i] = w2src[bq * 4096 + c * 128 + j];
    }
}

// ---------------------------------------------------------------------------
// Conv2d 32->32 k3 p1, 14x14, ReLU. 2 samples/block.
// ---------------------------------------------------------------------------
__global__ __launch_bounds__(256) void k_conv1(
    const float* __restrict__ in, const float* __restrict__ pk2,
    const float* __restrict__ bias, float* __restrict__ out)
{
    __shared__ float P[8208];   // [s2][c16][16 rows][16 cols] + overread pad
    const int tid = threadIdx.x;
    const int wv = __builtin_amdgcn_readfirstlane(tid >> 6);
    const int og = wv & 1, s = wv >> 1;
    const int lane = tid & 63;
    const bool active = lane < 56;
    int row = lane >> 2, tx0 = (lane & 3) * 4;
    if (!active) { row = 0; tx0 = 0; }
    const size_t b = (size_t)blockIdx.x * 2 + s;

    float acc[4][16];
    #pragma unroll
    for (int i = 0; i < 4; ++i)
        #pragma unroll
        for (int o = 0; o < 16; ++o) acc[i][o] = 0.f;

    for (int cc = 0; cc < 32; cc += 16) {
        __syncthreads();
        for (int e = tid; e < 8208; e += 256) P[e] = 0.f;
        __syncthreads();
        for (int e = tid; e < 6272; e += 256) {
            int si = e / 3136, rem = e - si * 3136;
            int c = rem / 196, p = rem % 196;
            P[((si * 16 + c) * 16 + p / 14 + 1) * 16 + (p % 14 + 1)] =
                in[((size_t)(blockIdx.x * 2 + si) * 32 + cc + c) * 196 + p];
        }
        __syncthreads();
        for (int cl = 0; cl < 16; ++cl) {
            const float* Pb = &P[((s * 16 + cl) * 16 + row) * 16 + tx0];
            float rowb[3][8];
            #pragma unroll
            for (int ky = 0; ky < 3; ++ky) {
                float4 a = *(const float4*)&Pb[ky * 16];
                float4 bq = *(const float4*)&Pb[ky * 16 + 4];
                rowb[ky][0] = a.x; rowb[ky][1] = a.y; rowb[ky][2] = a.z; rowb[ky][3] = a.w;
                rowb[ky][4] = bq.x; rowb[ky][5] = bq.y; rowb[ky][6] = bq.z; rowb[ky][7] = bq.w;
            }
            const float* wbase = pk2 + (size_t)(cc + cl) * 288 + og * 16;
            #pragma unroll
            for (int ky = 0; ky < 3; ++ky) {
                #pragma unroll
                for (int kx = 0; kx < 3; ++kx) {
                    const float* wt = wbase + (ky * 3 + kx) * 32;
                    #pragma unroll
                    for (int o = 0; o < 16; ++o) {
                        float w = wt[o];
                        #pragma unroll
                        for (int i = 0; i < 4; ++i)
                            acc[i][o] = fmaf(rowb[ky][i + kx], w, acc[i][o]);
                    }
                }
            }
        }
    }
    if (active) {
        #pragma unroll
        for (int o = 0; o < 16; ++o) {
            int oo = og * 16 + o;
            float bo = bias[oo];
            #pragma unroll
            for (int i = 0; i < 4; ++i) {
                int xx = tx0 + i;
                if (xx < 14)
                    out[(b * 32 + oo) * 196 + row * 14 + xx] = fmaxf(acc[i][o] + bo, 0.f);
            }
        }
    }
}

// ---------------------------------------------------------------------------
// FUSED: ConvTranspose2d 32->16 k4 s2 p1 (14x14->28x28, ReLU)
//        + Conv2d 16->8 k3 p1 (ReLU) + Conv2d 8->1 k1.
// One sample/block. convt2 output lives ONLY in LDS (zero-haloed [16][30][32])
// — eliminates the 51.4 MB/chunk d3 round-trip and conv23's re-staging.
// ---------------------------------------------------------------------------
__global__ __launch_bounds__(256) void k_convt23(
    const float* __restrict__ in, const float* __restrict__ pk3,
    const float* __restrict__ bt2, const float* __restrict__ pk4,
    const float* __restrict__ b2, const float* __restrict__ w3,
    const float* __restrict__ b3, float* __restrict__ out)
{
    __shared__ __align__(16) float P[16 * 960];   // 61440 B
    const int b = blockIdx.x, tid = threadIdx.x;

    // ---- Phase 1: convt2 (input tile in P[0..10240) as [c32][16r][20c]) ----
    for (int e = tid; e < 10240; e += 256) P[e] = 0.f;
    __syncthreads();
    for (int e = tid; e < 6272; e += 256) {
        int c = e / 196, p = e % 196;
        P[c * 320 + (p / 14 + 1) * 20 + (p % 14 + 1)] = in[(size_t)b * 6272 + e];
    }
    __syncthreads();

    const int q  = __builtin_amdgcn_readfirstlane(tid >> 6);
    const int py = q >> 1, px = q & 1;
    const int lane = tid & 63;
    const bool active = lane < 56;
    int ty = lane >> 2, tx0 = (lane & 3) * 4;
    if (!active) { ty = 0; tx0 = 0; }
    const int rbase = ty + py;

    float acc[4][16];
    #pragma unroll
    for (int i = 0; i < 4; ++i)
        #pragma unroll
        for (int o = 0; o < 16; ++o) acc[i][o] = 0.f;

    for (int c = 0; c < 32; ++c) {
        const float* Pb = &P[c * 320 + rbase * 20 + tx0];
        float raw[2][8];
        #pragma unroll
        for (int r2 = 0; r2 < 2; ++r2) {
            float4 a = *(const float4*)&Pb[r2 * 20];
            float4 bq = *(const float4*)&Pb[r2 * 20 + 4];
            raw[r2][0] = a.x; raw[r2][1] = a.y; raw[r2][2] = a.z; raw[r2][3] = a.w;
            raw[r2][4] = bq.x; raw[r2][5] = bq.y; raw[r2][6] = bq.z; raw[r2][7] = bq.w;
        }
        float rs[2][5];
        #pragma unroll
        for (int r2 = 0; r2 < 2; ++r2)
            #pragma unroll
            for (int j = 0; j < 5; ++j) rs[r2][j] = px ? raw[r2][j + 1] : raw[r2][j];
        const float* wq = pk3 + (size_t)((c * 4 + q) * 4) * 16;
        #pragma unroll
        for (int t = 0; t < 4; ++t) {
            int wy = t >> 1, wx = t & 1;
            const float* wt = wq + t * 16;
            #pragma unroll
            for (int o = 0; o < 16; ++o) {
                float w = wt[o];
                #pragma unroll
                for (int i = 0; i < 4; ++i)
                    acc[i][o] = fmaf(rs[wy][i + wx], w, acc[i][o]);
            }
        }
    }

    // ---- Phase 2: ReLU'd convt2 output -> zero-haloed P[16][30][32] ----
    __syncthreads();                       // all reads of input tile done
    for (int e = tid; e < 15360; e += 256) P[e] = 0.f;
    __syncthreads();
    if (active) {
        const int y = 2 * ty + py;
        #pragma unroll
        for (int o = 0; o < 16; ++o) {
            float bo = bt2[o];
            #pragma unroll
            for (int i = 0; i < 4; ++i) {
                int xt = tx0 + i;
                if (xt < 14)
                    P[(o * 30 + y + 1) * 32 + (2 * xt + px + 1)] = fmaxf(acc[i][o] + bo, 0.f);
            }
        }
    }
    __syncthreads();

    // ---- Phase 3: conv2 (16->8, k3, ReLU) + conv3 (8->1, k1) from LDS ----
    const bool active2 = tid < 196;
    int row = active2 ? tid / 7 : 0;
    int tx0b = active2 ? (tid % 7) * 4 : 0;

    float acc2[4][8];
    #pragma unroll
    for (int i = 0; i < 4; ++i)
        #pragma unroll
        for (int o = 0; o < 8; ++o) acc2[i][o] = 0.f;

    for (int cl = 0; cl < 16; ++cl) {
        const float* Pb = &P[(cl * 30 + row) * 32 + tx0b];
        const float* wb = pk4 + (size_t)cl * 72;
        #pragma unroll
        for (int ky = 0; ky < 3; ++ky) {
            float4 a = *(const float4*)&Pb[ky * 32];
            float4 bq = *(const float4*)&Pb[ky * 32 + 4];
            float rowb[8] = {a.x, a.y, a.z, a.w, bq.x, bq.y, bq.z, bq.w};
            #pragma unroll
            for (int kx = 0; kx < 3; ++kx) {
                const float* wt = wb + (ky * 3 + kx) * 8;
                #pragma unroll
                for (int o = 0; o < 8; ++o) {
                    float w = wt[o];
                    #pragma unroll
                    for (int i = 0; i < 4; ++i)
                        acc2[i][o] = fmaf(rowb[i + kx], w, acc2[i][o]);
                }
            }
        }
    }
    if (active2) {
        const float bias3 = b3[0];
        #pragma unroll
        for (int i = 0; i < 4; ++i) {
            float r = bias3;
            #pragma unroll
            for (int o = 0; o < 8; ++o) r += fmaxf(acc2[i][o] + b2[o], 0.f) * w3[o];
            out[(size_t)b * 784 + row * 28 + tx0b + i] = r;
        }
    }
}

// ---------------------------------------------------------------------------
extern "C" void kernel_launch(void* const* d_in, const int* in_sizes, int n_in,
                              void* d_out, int out_size, void* d_ws, size_t ws_size,
                              hipStream_t stream)
{
    const float* x       = (const float*)d_in[0];
    const float* patch_w = (const float*)d_in[1];
    const float* patch_b = (const float*)d_in[2];
    const float* ln1g    = (const float*)d_in[3];
    const float* ln1b    = (const float*)d_in[4];
    const float* wi      = (const float*)d_in[5];
    const float* bi      = (const float*)d_in[6];
    const float* wo      = (const float*)d_in[7];
    const float* bo      = (const float*)d_in[8];
    const float* ln2g    = (const float*)d_in[9];
    const float* ln2b    = (const float*)d_in[10];
    const float* w1      = (const float*)d_in[11];
    const float* b1      = (const float*)d_in[12];
    const float* w2      = (const float*)d_in[13];
    const float* b2      = (const float*)d_in[14];
    const float* lat_w   = (const float*)d_in[15];
    const float* lat_b   = (const float*)d_in[16];
    const float* memory  = (const float*)d_in[17];
    const float* dec_w   = (const float*)d_in[18];
    const float* dec_b   = (const float*)d_in[19];
    const float* upt1_w  = (const float*)d_in[20];
    const float* upt1_b  = (const float*)d_in[21];
    const float* c1_w    = (const float*)d_in[22];
    const float* c1_b    = (const float*)d_in[23];
    const float* upt2_w  = (const float*)d_in[24];
    const float* upt2_b  = (const float*)d_in[25];
    const float* c2_w    = (const float*)d_in[26];
    const float* c2_b    = (const float*)d_in[27];
    const float* c3_w    = (const float*)d_in[28];
    const float* c3_b    = (const float*)d_in[29];
    float* outp = (float*)d_out;

    float* ws = (float*)d_ws;
    size_t off = 0;
    auto alloc = [&](size_t n) { float* p = ws + off; off += (n + 63) & ~(size_t)63; return p; };
    float* tokens     = alloc((size_t)B_TOT * 1568);
    float* latent     = alloc((size_t)B_TOT * 256);
    float* dots       = alloc((size_t)B_TOT * 4096);
    float* mem_latent = alloc((size_t)B_TOT * 256);
    float* inv_mn     = alloc(4096);
    float* pk2        = alloc(9216);
    float* pk3        = alloc(8192);
    float* pk4        = alloc(1152);
    float* pk5        = alloc(8192);
    float* Wf         = alloc((size_t)6272 * 256);
    float* bf         = alloc(6272);
    float* d1         = alloc((size_t)CHUNK * 6272);
    float* d2         = alloc((size_t)CHUNK * 6272);
    (void)in_sizes; (void)n_in; (void)out_size; (void)ws_size;

    // Weight repack + dec/convt1 algebraic fusion
    k_pack<<<36, 256, 0, stream>>>(c1_w, upt2_w, c2_w, w2, pk2, pk3, pk4, pk5);
    k_fuse<<<6272, 256, 0, stream>>>(upt1_w, upt1_b, dec_w, dec_b, Wf, bf);

    // Encoder (wave-per-sample)
    k_tokens<<<B_TOT / 4, 256, 0, stream>>>(x, patch_w, patch_b, ln1g, ln1b, wi, bi,
                                            wo, bo, ln2g, ln2b, w1, b1, pk5, b2, tokens);
    k_gemm<<<dim3(256 / 64, B_TOT / 128), 256, 0, stream>>>(tokens, lat_w, lat_b, latent,
                                                            B_TOT, 256, 1568, 0);
    k_mnorm<<<4096, 256, 0, stream>>>(memory, inv_mn);
    k_gemm<<<dim3(4096 / 64, B_TOT / 128), 256, 0, stream>>>(latent, memory, nullptr, dots,
                                                             B_TOT, 4096, 256, 0);
    k_memread<<<B_TOT, 256, 0, stream>>>(latent, dots, inv_mn, memory, mem_latent);

    // Decoder, chunked over batch. Fused dec+convt1 GEMM -> d1; conv1 -> d2;
    // fused convt2+conv2+conv3 -> output (no d3 round-trip).
    for (int c = 0; c < B_TOT / CHUNK; ++c) {
        const float* ml = mem_latent + (size_t)c * CHUNK * 256;
        k_gemm<<<dim3(6272 / 64, CHUNK / 128), 256, 0, stream>>>(ml, Wf, bf, d1,
                                                                 CHUNK, 6272, 256, 1);
        k_conv1  <<<CHUNK / 2, 256, 0, stream>>>(d1, pk2, c1_b, d2);
        k_convt23<<<CHUNK, 256, 0, stream>>>(d2, pk3, upt2_b, pk4, c2_b, c3_w, c3_b,
                                             outp + (size_t)c * CHUNK * 784);
    }
}

// Round 7
// 1826.697 us; speedup vs baseline: 1.1050x; 1.1050x over previous
//
#include <hip/hip_runtime.h>
#include <math.h>

#define B_TOT 4096
#define CHUNK 1024

typedef _Float16 half_t;
typedef _Float16 h2 __attribute__((ext_vector_type(2)));

#if __has_builtin(__builtin_amdgcn_fdot2)
#define FDOT2(a, b, c) __builtin_amdgcn_fdot2((a), (b), (c), false)
#else
#define FDOT2(a, b, c) fmaf((float)(a)[1], (float)(b)[1], fmaf((float)(a)[0], (float)(b)[0], (c)))
#endif

// Per-wave LDS: K 49x36 halves (72B rows, fp16), V 49x34 floats (136B rows, fp32).
// Block: 4 waves KV (40768) + wi stage slot (12288) = 53056 B -> 3 blocks/CU.
// FF weights (32 KB) overlay [0,32768) (over KV) after attention, barrier-guarded.
// V stays fp32: fp16 V measured absmax 2.9e-3 > 1.19e-3 threshold (round 4).
#define KSTR 36          // halves per K row
#define VSTR 34          // floats per V row
#define KBYTES (49 * 72)
#define WAVE_LDS (49 * 72 + 49 * 136)  // 10192
#define WI_OFF  (4 * WAVE_LDS)         // 40768
#define BLOCK_LDS (WI_OFF + 12288)     // 53056

// ---------------------------------------------------------------------------
// Fused: patch conv (1->32, k4 s4) + 2 transformer blocks.
// ---------------------------------------------------------------------------
__global__ __launch_bounds__(256) void k_tokens(
    const float* __restrict__ x, const float* __restrict__ pw, const float* __restrict__ pb,
    const float* __restrict__ ln1g, const float* __restrict__ ln1b,
    const float* __restrict__ wi, const float* __restrict__ bi,
    const float* __restrict__ wo, const float* __restrict__ bo,
    const float* __restrict__ ln2g, const float* __restrict__ ln2b,
    const float* __restrict__ w1, const float* __restrict__ fb1,
    const float* __restrict__ w2t, const float* __restrict__ fb2,
    float* __restrict__ tokens)
{
    __shared__ __align__(16) unsigned char Lraw[BLOCK_LDS];
    const int tid = threadIdx.x;
    const int wv = tid >> 6, lane = tid & 63;
    const int b = blockIdx.x * 4 + wv;
    half_t* Kb = (half_t*)(Lraw + wv * WAVE_LDS);
    float*  Vb = (float*)(Lraw + wv * WAVE_LDS + KBYTES);
    const float* wiL = (const float*)(Lraw + WI_OFF);
    float* Lf = (float*)Lraw;            // FF-weight overlay (block-wide)
    const bool is_tok = lane < 49;
    const int s = is_tok ? lane : 48;
    const int py = s / 7, px = s % 7;

    // --- patch conv: direct float4 loads (rows are 16B-aligned) ---
    float xv[16];
    const float* xb = x + (size_t)b * 784 + py * 112 + px * 4;
    #pragma unroll
    for (int r = 0; r < 4; ++r) {
        float4 vq = *(const float4*)(xb + r * 28);
        xv[4 * r + 0] = vq.x; xv[4 * r + 1] = vq.y;
        xv[4 * r + 2] = vq.z; xv[4 * r + 3] = vq.w;
    }
    float t[32];
    #pragma unroll 4
    for (int c = 0; c < 32; ++c) {
        float a = pb[c];
        const float* wr = pw + c * 16;
        #pragma unroll
        for (int i = 0; i < 16; ++i) a = fmaf(xv[i], wr[i], a);
        t[c] = a;
    }

    for (int blk = 0; blk < 2; ++blk) {
        const float* bib = bi + blk * 96;

        // --- LN1 ---
        float mu = 0.f;
        #pragma unroll
        for (int c = 0; c < 32; ++c) mu += t[c];
        mu *= 0.03125f;
        float var = 0.f;
        #pragma unroll
        for (int c = 0; c < 32; ++c) { float d = t[c] - mu; var = fmaf(d, d, var); }
        float rstd = rsqrtf(var * 0.03125f + 1e-5f);
        float xn[32];
        #pragma unroll
        for (int c = 0; c < 32; ++c)
            xn[c] = (t[c] - mu) * rstd * ln1g[blk * 32 + c] + ln1b[blk * 32 + c];

        __syncthreads();   // (A) prior-phase LDS reads complete before overwrite

        // --- stage qkv in-proj weights (12 KB) into LDS ---
        {
            const float4* srcw = (const float4*)(wi + blk * 3072);
            float4* dstw = (float4*)(Lraw + WI_OFF);
            for (int e = tid; e < 768; e += 256) dstw[e] = srcw[e];
        }
        __syncthreads();   // (A2) wi visible

        // --- K projection -> LDS fp16 (broadcast b128 weight reads) ---
        #pragma unroll 4
        for (int d = 0; d < 32; ++d) {
            const float* wr = wiL + (32 + d) * 32;
            float a0 = bib[32 + d], a1 = 0.f;
            #pragma unroll
            for (int c2 = 0; c2 < 4; ++c2) {
                float4 wq = *(const float4*)&wr[4 * c2];
                a0 = fmaf(xn[4 * c2],     wq.x, a0);
                a0 = fmaf(xn[4 * c2 + 1], wq.y, a0);
                a0 = fmaf(xn[4 * c2 + 2], wq.z, a0);
                a0 = fmaf(xn[4 * c2 + 3], wq.w, a0);
            }
            #pragma unroll
            for (int c2 = 4; c2 < 8; ++c2) {
                float4 wq = *(const float4*)&wr[4 * c2];
                a1 = fmaf(xn[4 * c2],     wq.x, a1);
                a1 = fmaf(xn[4 * c2 + 1], wq.y, a1);
                a1 = fmaf(xn[4 * c2 + 2], wq.z, a1);
                a1 = fmaf(xn[4 * c2 + 3], wq.w, a1);
            }
            if (is_tok) Kb[s * KSTR + d] = (half_t)(a0 + a1);
        }
        // --- V projection -> LDS fp32 ---
        #pragma unroll 4
        for (int d = 0; d < 32; ++d) {
            const float* wr = wiL + (64 + d) * 32;
            float a0 = bib[64 + d], a1 = 0.f;
            #pragma unroll
            for (int c2 = 0; c2 < 4; ++c2) {
                float4 wq = *(const float4*)&wr[4 * c2];
                a0 = fmaf(xn[4 * c2],     wq.x, a0);
                a0 = fmaf(xn[4 * c2 + 1], wq.y, a0);
                a0 = fmaf(xn[4 * c2 + 2], wq.z, a0);
                a0 = fmaf(xn[4 * c2 + 3], wq.w, a0);
            }
            #pragma unroll
            for (int c2 = 4; c2 < 8; ++c2) {
                float4 wq = *(const float4*)&wr[4 * c2];
                a1 = fmaf(xn[4 * c2],     wq.x, a1);
                a1 = fmaf(xn[4 * c2 + 1], wq.y, a1);
                a1 = fmaf(xn[4 * c2 + 2], wq.z, a1);
                a1 = fmaf(xn[4 * c2 + 3], wq.w, a1);
            }
            if (is_tok) Vb[s * VSTR + d] = a0 + a1;
        }
        // --- Q projection (scaled), packed to half2 for fdot2 ---
        float q0[32];
        #pragma unroll 4
        for (int d = 0; d < 32; ++d) {
            const float* wr = wiL + d * 32;
            float a0 = bib[d], a1 = 0.f;
            #pragma unroll
            for (int c2 = 0; c2 < 4; ++c2) {
                float4 wq = *(const float4*)&wr[4 * c2];
                a0 = fmaf(xn[4 * c2],     wq.x, a0);
                a0 = fmaf(xn[4 * c2 + 1], wq.y, a0);
                a0 = fmaf(xn[4 * c2 + 2], wq.z, a0);
                a0 = fmaf(xn[4 * c2 + 3], wq.w, a0);
            }
            #pragma unroll
            for (int c2 = 4; c2 < 8; ++c2) {
                float4 wq = *(const float4*)&wr[4 * c2];
                a1 = fmaf(xn[4 * c2],     wq.x, a1);
                a1 = fmaf(xn[4 * c2 + 1], wq.y, a1);
                a1 = fmaf(xn[4 * c2 + 2], wq.z, a1);
                a1 = fmaf(xn[4 * c2 + 3], wq.w, a1);
            }
            q0[d] = (a0 + a1) * 0.25f;
        }
        h2 qh[16];
        #pragma unroll
        for (int i = 0; i < 16; ++i) {
            h2 hh; hh[0] = (half_t)q0[2 * i]; hh[1] = (half_t)q0[2 * i + 1];
            qh[i] = hh;
        }

        // wave-local fence: own K/V ds_writes visible before broadcast reads
        __asm__ volatile("s_waitcnt lgkmcnt(0)" ::: "memory");

        // --- attention: 2 heads of 16 dims, softmax without running max ---
        float o[32];
        #pragma unroll
        for (int d = 0; d < 32; ++d) o[d] = 0.f;
        float l0 = 0.f, l1 = 0.f;
        union H4 { double qd; h2 p[2]; };
        for (int j = 0; j < 49; ++j) {
            const double* kr = (const double*)(Kb + j * KSTR);
            const float* vr = Vb + j * VSTR;
            H4 u0, u1, u2, u3, w0, w1h, w2h, w3;
            u0.qd = kr[0]; u1.qd = kr[1]; u2.qd = kr[2]; u3.qd = kr[3];
            w0.qd = kr[4]; w1h.qd = kr[5]; w2h.qd = kr[6]; w3.qd = kr[7];
            float s0a = 0.f, s0b = 0.f, s1a = 0.f, s1b = 0.f;
            s0a = FDOT2(u0.p[0], qh[0], s0a); s0a = FDOT2(u0.p[1], qh[1], s0a);
            s0b = FDOT2(u1.p[0], qh[2], s0b); s0b = FDOT2(u1.p[1], qh[3], s0b);
            s0a = FDOT2(u2.p[0], qh[4], s0a); s0a = FDOT2(u2.p[1], qh[5], s0a);
            s0b = FDOT2(u3.p[0], qh[6], s0b); s0b = FDOT2(u3.p[1], qh[7], s0b);
            s1a = FDOT2(w0.p[0], qh[8], s1a); s1a = FDOT2(w0.p[1], qh[9], s1a);
            s1b = FDOT2(w1h.p[0], qh[10], s1b); s1b = FDOT2(w1h.p[1], qh[11], s1b);
            s1a = FDOT2(w2h.p[0], qh[12], s1a); s1a = FDOT2(w2h.p[1], qh[13], s1a);
            s1b = FDOT2(w3.p[0], qh[14], s1b); s1b = FDOT2(w3.p[1], qh[15], s1b);
            float p0 = __expf(s0a + s0b), p1 = __expf(s1a + s1b);
            l0 += p0; l1 += p1;
            #pragma unroll
            for (int i = 0; i < 8; ++i) {
                float2 va = *(const float2*)&vr[2 * i];
                o[2 * i]     = fmaf(p0, va.x, o[2 * i]);
                o[2 * i + 1] = fmaf(p0, va.y, o[2 * i + 1]);
                float2 vc = *(const float2*)&vr[16 + 2 * i];
                o[16 + 2 * i]     = fmaf(p1, vc.x, o[16 + 2 * i]);
                o[16 + 2 * i + 1] = fmaf(p1, vc.y, o[16 + 2 * i + 1]);
            }
        }
        float il0 = 1.f / l0, il1 = 1.f / l1;
        #pragma unroll
        for (int d = 0; d < 16; ++d) { o[d] *= il0; o[16 + d] *= il1; }

        // --- out projection + residual (wave-uniform global weights, 4 KB) ---
        #pragma unroll
        for (int c = 0; c < 32; ++c) {
            const float* wr = wo + blk * 1024 + c * 32;
            float a = bo[blk * 32 + c];
            #pragma unroll
            for (int k2 = 0; k2 < 32; ++k2) a = fmaf(o[k2], wr[k2], a);
            t[c] += a;
        }

        // --- LN2 ---
        mu = 0.f;
        #pragma unroll
        for (int c = 0; c < 32; ++c) mu += t[c];
        mu *= 0.03125f;
        var = 0.f;
        #pragma unroll
        for (int c = 0; c < 32; ++c) { float d = t[c] - mu; var = fmaf(d, d, var); }
        rstd = rsqrtf(var * 0.03125f + 1e-5f);
        #pragma unroll
        for (int c = 0; c < 32; ++c)
            xn[c] = (t[c] - mu) * rstd * ln2g[blk * 32 + c] + ln2b[blk * 32 + c];

        __syncthreads();   // (C) all waves done reading K/V + wi

        // --- stage FF weights into LDS (overlay over KV), float4 copy ---
        {
            const float4* src1 = (const float4*)(w1 + blk * 4096);
            const float4* src2 = (const float4*)(w2t + blk * 4096);
            float4* dst = (float4*)Lraw;
            for (int e = tid; e < 1024; e += 256) dst[e] = src1[e];
            for (int e = tid; e < 1024; e += 256) dst[1024 + e] = src2[e];
        }
        __syncthreads();   // (D) FF weights visible

        // --- FF from LDS: broadcast ds_read_b128 rows ---
        const float* w2L = Lf + 4096;
        #pragma unroll 2
        for (int j = 0; j < 128; ++j) {
            const float* wr = Lf + j * 32;
            float ha = fb1[blk * 128 + j], hb = 0.f;
            #pragma unroll
            for (int c2 = 0; c2 < 4; ++c2) {
                float4 wq = *(const float4*)&wr[4 * c2];
                ha = fmaf(xn[4 * c2],     wq.x, ha);
                ha = fmaf(xn[4 * c2 + 1], wq.y, ha);
                ha = fmaf(xn[4 * c2 + 2], wq.z, ha);
                ha = fmaf(xn[4 * c2 + 3], wq.w, ha);
            }
            #pragma unroll
            for (int c2 = 4; c2 < 8; ++c2) {
                float4 wq = *(const float4*)&wr[4 * c2];
                hb = fmaf(xn[4 * c2],     wq.x, hb);
                hb = fmaf(xn[4 * c2 + 1], wq.y, hb);
                hb = fmaf(xn[4 * c2 + 2], wq.z, hb);
                hb = fmaf(xn[4 * c2 + 3], wq.w, hb);
            }
            float h = ha + hb;
            h = 0.5f * h * (1.f + erff(h * 0.7071067811865476f));
            const float* w2r = w2L + j * 32;
            #pragma unroll
            for (int c2 = 0; c2 < 8; ++c2) {
                float4 wq = *(const float4*)&w2r[4 * c2];
                t[4 * c2]     = fmaf(h, wq.x, t[4 * c2]);
                t[4 * c2 + 1] = fmaf(h, wq.y, t[4 * c2 + 1]);
                t[4 * c2 + 2] = fmaf(h, wq.z, t[4 * c2 + 2]);
                t[4 * c2 + 3] = fmaf(h, wq.w, t[4 * c2 + 3]);
            }
        }
        #pragma unroll
        for (int c = 0; c < 32; ++c) t[c] += fb2[blk * 32 + c];
    }

    if (is_tok) {
        float* op = tokens + (size_t)b * 1568 + s * 32;
        #pragma unroll
        for (int c = 0; c < 32; c += 4) {
            float4 vv = make_float4(t[c], t[c + 1], t[c + 2], t[c + 3]);
            *(float4*)&op[c] = vv;
        }
    }
}

// ---------------------------------------------------------------------------
// C[M,N] = A[M,K] @ B[N,K]^T (+bias, optional ReLU). 128x64 tile, BK=16,
// 8x4 microtile.
// ---------------------------------------------------------------------------
__global__ __launch_bounds__(256) void k_gemm(
    const float* __restrict__ A, const float* __restrict__ Bm,
    const float* __restrict__ bias, float* __restrict__ C,
    int M, int N, int K, int relu)
{
    __shared__ float As[16 * 132];
    __shared__ float Bs[16 * 68];
    const int n0 = blockIdx.x * 64, m0 = blockIdx.y * 128;
    const int tid = threadIdx.x;
    const int tx = tid & 15, ty = tid >> 4;
    const int lr = tid >> 1, lk = (tid & 1) * 8;
    const int br = tid >> 2, bk = (tid & 3) * 4;
    float acc[8][4] = {{0.f}};
    for (int k0 = 0; k0 < K; k0 += 16) {
        float4 av0 = *(const float4*)&A[(size_t)(m0 + lr) * K + k0 + lk];
        float4 av1 = *(const float4*)&A[(size_t)(m0 + lr) * K + k0 + lk + 4];
        float4 bv0 = *(const float4*)&Bm[(size_t)(n0 + br) * K + k0 + bk];
        As[(lk + 0) * 132 + lr] = av0.x;
        As[(lk + 1) * 132 + lr] = av0.y;
        As[(lk + 2) * 132 + lr] = av0.z;
        As[(lk + 3) * 132 + lr] = av0.w;
        As[(lk + 4) * 132 + lr] = av1.x;
        As[(lk + 5) * 132 + lr] = av1.y;
        As[(lk + 6) * 132 + lr] = av1.z;
        As[(lk + 7) * 132 + lr] = av1.w;
        Bs[(bk + 0) * 68 + br] = bv0.x;
        Bs[(bk + 1) * 68 + br] = bv0.y;
        Bs[(bk + 2) * 68 + br] = bv0.z;
        Bs[(bk + 3) * 68 + br] = bv0.w;
        __syncthreads();
        #pragma unroll
        for (int k = 0; k < 16; ++k) {
            float4 a0 = *(const float4*)&As[k * 132 + ty * 8];
            float4 a1 = *(const float4*)&As[k * 132 + ty * 8 + 4];
            float4 bv = *(const float4*)&Bs[k * 68 + tx * 4];
            float a8[8] = {a0.x, a0.y, a0.z, a0.w, a1.x, a1.y, a1.z, a1.w};
            float b4[4] = {bv.x, bv.y, bv.z, bv.w};
            #pragma unroll
            for (int i = 0; i < 8; ++i)
                #pragma unroll
                for (int j = 0; j < 4; ++j)
                    acc[i][j] = fmaf(a8[i], b4[j], acc[i][j]);
        }
        __syncthreads();
    }
    #pragma unroll
    for (int i = 0; i < 8; ++i) {
        int m = m0 + ty * 8 + i;
        #pragma unroll
        for (int j = 0; j < 4; ++j) {
            int n = n0 + tx * 4 + j;
            float v = acc[i][j] + (bias ? bias[n] : 0.f);
            if (relu) v = fmaxf(v, 0.f);
            C[(size_t)m * N + n] = v;
        }
    }
}

// ---------------------------------------------------------------------------
// Fuse dec (linear 256->3136) with convt1 (convT 64->32 k4 s2 p1).
// ---------------------------------------------------------------------------
__global__ __launch_bounds__(256) void k_fuse(
    const float* __restrict__ wt1, const float* __restrict__ upt1_b,
    const float* __restrict__ dec_w, const float* __restrict__ dec_b,
    float* __restrict__ Wf, float* __restrict__ bf)
{
    const int n = blockIdx.x;
    const int k = threadIdx.x;
    const int o = n / 196, p = n % 196, y = p / 14, x = p % 14;
    float acc = 0.f, bacc = 0.f;
    for (int ky = 0; ky < 4; ++ky) {
        int iyn = y + 1 - ky;
        if (iyn < 0 || (iyn & 1)) continue;
        int iy = iyn >> 1;
        if (iy > 6) continue;
        for (int kx = 0; kx < 4; ++kx) {
            int ixn = x + 1 - kx;
            if (ixn < 0 || (ixn & 1)) continue;
            int ix = ixn >> 1;
            if (ix > 6) continue;
            for (int c = 0; c < 64; ++c) {
                float w = wt1[((c * 32 + o) * 4 + ky) * 4 + kx];
                int row = c * 49 + iy * 7 + ix;
                acc  = fmaf(w, dec_w[(size_t)row * 256 + k], acc);
                bacc = fmaf(w, dec_b[row], bacc);
            }
        }
    }
    Wf[(size_t)n * 256 + k] = acc;
    if (k == 0) bf[n] = bacc + upt1_b[o];
}

// ---------------------------------------------------------------------------
__global__ __launch_bounds__(256) void k_mnorm(const float* __restrict__ mem, float* __restrict__ inv_norm)
{
    __shared__ float red[256];
    const int row = blockIdx.x, tid = threadIdx.x;
    float v = mem[(size_t)row * 256 + tid];
    red[tid] = v * v;
    __syncthreads();
    for (int s = 128; s > 0; s >>= 1) {
        if (tid < s) red[tid] += red[tid + s];
        __syncthreads();
    }
    if (tid == 0) inv_norm[row] = 1.f / fmaxf(sqrtf(red[0]), 1e-12f);
}

// ---------------------------------------------------------------------------
__global__ __launch_bounds__(256) void k_memread(
    const float* __restrict__ latent, const float* __restrict__ dots,
    const float* __restrict__ inv_mn, const float* __restrict__ mem,
    float* __restrict__ out)
{
    __shared__ float red[256];
    __shared__ int   redi[256];
    __shared__ float inv_x_s;
    const int b = blockIdx.x, tid = threadIdx.x;
    float lx = latent[(size_t)b * 256 + tid];
    red[tid] = lx * lx;
    __syncthreads();
    for (int s = 128; s > 0; s >>= 1) {
        if (tid < s) red[tid] += red[tid + s];
        __syncthreads();
    }
    if (tid == 0) inv_x_s = 1.f / fmaxf(sqrtf(red[0]), 1e-12f);
    __syncthreads();
    const float inv_x = inv_x_s;

    float vals[16];
    for (int j = 0; j < 16; ++j) {
        int m = tid + j * 256;
        vals[j] = dots[(size_t)b * 4096 + m] * inv_mn[m] * inv_x;
    }
    float tv[10]; int ti[10];
    for (int t = 0; t < 10; ++t) {
        float bv = -1e30f; int bidx = 0x7fffffff;
        for (int j = 0; j < 16; ++j) {
            int m = tid + j * 256;
            float v = vals[j];
            if (v > bv || (v == bv && m < bidx)) { bv = v; bidx = m; }
        }
        red[tid] = bv; redi[tid] = bidx;
        __syncthreads();
        for (int s = 128; s > 0; s >>= 1) {
            if (tid < s) {
                float v2 = red[tid + s]; int i2 = redi[tid + s];
                if (v2 > red[tid] || (v2 == red[tid] && i2 < redi[tid])) { red[tid] = v2; redi[tid] = i2; }
            }
            __syncthreads();
        }
        int sel = redi[0];
        tv[t] = red[0]; ti[t] = sel;
        if ((sel & 255) == tid) vals[sel >> 8] = -1e30f;
        __syncthreads();
    }
    float w[10], wsum = 0.f;
    for (int t = 0; t < 10; ++t) { w[t] = expf(tv[t] - tv[0]); wsum += w[t]; }
    float inv_ws = 1.f / wsum;
    float acc = 0.f;
    for (int t = 0; t < 10; ++t) acc += (w[t] * inv_ws) * mem[(size_t)ti[t] * 256 + tid];
    out[(size_t)b * 256 + tid] = acc;
}

// ---------------------------------------------------------------------------
// Weight repack.
// ---------------------------------------------------------------------------
__global__ __launch_bounds__(256) void k_pack(
    const float* __restrict__ wc1, const float* __restrict__ wt2,
    const float* __restrict__ wc2, const float* __restrict__ w2src,
    float* __restrict__ pk2, float* __restrict__ pk3,
    float* __restrict__ pk4, float* __restrict__ pk5)
{
    int i = blockIdx.x * 256 + threadIdx.x;
    if (i < 9216) {
        int o = i & 31, tap = (i >> 5) % 9, c = i / 288;
        pk2[i] = wc1[(o * 32 + c) * 9 + tap];
    }
    if (i < 8192) {
        int o = i & 15, t = (i >> 4) & 3, q = (i >> 6) & 3, c = i >> 8;
        int wy = t >> 1, wx = t & 1, py = q >> 1, px = q & 1;
        int ky = 3 - py - 2 * wy, kx = 3 - px - 2 * wx;
        pk3[i] = wt2[((c * 16 + o) * 4 + ky) * 4 + kx];
    }
    if (i < 1152) {
        int o = i & 7, tap = (i >> 3) % 9, c = i / 72;
        pk4[i] = wc2[(o * 16 + c) * 9 + tap];
    }
    if (i < 8192) {
        int c = i & 31, j = (i >> 5) & 127, bq = i >> 12;
        pk5[i] = w2src[bq * 4096 + c * 128 + j];
    }
}

// ---------------------------------------------------------------------------
// Conv2d 32->32 k3 p1, 14x14, ReLU. 2 samples/block.
// ---------------------------------------------------------------------------
__global__ __launch_bounds__(256) void k_conv1(
    const float* __restrict__ in, const float* __restrict__ pk2,
    const float* __restrict__ bias, float* __restrict__ out)
{
    __shared__ float P[8208];   // [s2][c16][16 rows][16 cols] + overread pad
    const int tid = threadIdx.x;
    const int wv = __builtin_amdgcn_readfirstlane(tid >> 6);
    const int og = wv & 1, s = wv >> 1;
    const int lane = tid & 63;
    const bool active = lane < 56;
    int row = lane >> 2, tx0 = (lane & 3) * 4;
    if (!active) { row = 0; tx0 = 0; }
    const size_t b = (size_t)blockIdx.x * 2 + s;

    float acc[4][16];
    #pragma unroll
    for (int i = 0; i < 4; ++i)
        #pragma unroll
        for (int o = 0; o < 16; ++o) acc[i][o] = 0.f;

    for (int cc = 0; cc < 32; cc += 16) {
        __syncthreads();
        for (int e = tid; e < 8208; e += 256) P[e] = 0.f;
        __syncthreads();
        for (int e = tid; e < 6272; e += 256) {
            int si = e / 3136, rem = e - si * 3136;
            int c = rem / 196, p = rem % 196;
            P[((si * 16 + c) * 16 + p / 14 + 1) * 16 + (p % 14 + 1)] =
                in[((size_t)(blockIdx.x * 2 + si) * 32 + cc + c) * 196 + p];
        }
        __syncthreads();
        for (int cl = 0; cl < 16; ++cl) {
            const float* Pb = &P[((s * 16 + cl) * 16 + row) * 16 + tx0];
            float rowb[3][8];
            #pragma unroll
            for (int ky = 0; ky < 3; ++ky) {
                float4 a = *(const float4*)&Pb[ky * 16];
                float4 bq = *(const float4*)&Pb[ky * 16 + 4];
                rowb[ky][0] = a.x; rowb[ky][1] = a.y; rowb[ky][2] = a.z; rowb[ky][3] = a.w;
                rowb[ky][4] = bq.x; rowb[ky][5] = bq.y; rowb[ky][6] = bq.z; rowb[ky][7] = bq.w;
            }
            const float* wbase = pk2 + (size_t)(cc + cl) * 288 + og * 16;
            #pragma unroll
            for (int ky = 0; ky < 3; ++ky) {
                #pragma unroll
                for (int kx = 0; kx < 3; ++kx) {
                    const float* wt = wbase + (ky * 3 + kx) * 32;
                    #pragma unroll
                    for (int o = 0; o < 16; ++o) {
                        float w = wt[o];
                        #pragma unroll
                        for (int i = 0; i < 4; ++i)
                            acc[i][o] = fmaf(rowb[ky][i + kx], w, acc[i][o]);
                    }
                }
            }
        }
    }
    if (active) {
        #pragma unroll
        for (int o = 0; o < 16; ++o) {
            int oo = og * 16 + o;
            float bo = bias[oo];
            #pragma unroll
            for (int i = 0; i < 4; ++i) {
                int xx = tx0 + i;
                if (xx < 14)
                    out[(b * 32 + oo) * 196 + row * 14 + xx] = fmaxf(acc[i][o] + bo, 0.f);
            }
        }
    }
}

// ---------------------------------------------------------------------------
// FUSED: ConvTranspose2d 32->16 k4 s2 p1 (14x14->28x28, ReLU)
//        + Conv2d 16->8 k3 p1 (ReLU) + Conv2d 8->1 k1. One sample/block.
// convt2 output lives only in registers+LDS (no d3 round-trip). Phase 2/3
// process the 16 channels in TWO groups of 8 so the LDS stays at 40960 B
// (input tile [32][16][20] = 40960 B, group tile [8][30][32] = 30720 B,
// overlaid) -> 4 blocks/CU. Round-6's single-shot 61440 B variant dropped
// to 2 blocks/CU and regressed ~30%.
// ---------------------------------------------------------------------------
__global__ __launch_bounds__(256) void k_convt23(
    const float* __restrict__ in, const float* __restrict__ pk3,
    const float* __restrict__ bt2, const float* __restrict__ pk4,
    const float* __restrict__ b2, const float* __restrict__ w3,
    const float* __restrict__ b3, float* __restrict__ out)
{
    __shared__ __align__(16) float P[10240];   // 40960 B
    const int b = blockIdx.x, tid = threadIdx.x;

    // ---- Phase 1: convt2 from input tile [c32][16r][20c] ----
    for (int e = tid; e < 10240; e += 256) P[e] = 0.f;
    __syncthreads();
    for (int e = tid; e < 6272; e += 256) {
        int c = e / 196, p = e % 196;
        P[c * 320 + (p / 14 + 1) * 20 + (p % 14 + 1)] = in[(size_t)b * 6272 + e];
    }
    __syncthreads();

    const int q  = __builtin_amdgcn_readfirstlane(tid >> 6);
    const int py = q >> 1, px = q & 1;
    const int lane = tid & 63;
    const bool active = lane < 56;
    int ty = lane >> 2, tx0 = (lane & 3) * 4;
    if (!active) { ty = 0; tx0 = 0; }
    const int rbase = ty + py;

    float acc[4][16];
    #pragma unroll
    for (int i = 0; i < 4; ++i)
        #pragma unroll
        for (int o = 0; o < 16; ++o) acc[i][o] = 0.f;

    for (int c = 0; c < 32; ++c) {
        const float* Pb = &P[c * 320 + rbase * 20 + tx0];
        float raw[2][8];
        #pragma unroll
        for (int r2 = 0; r2 < 2; ++r2) {
            float4 a = *(const float4*)&Pb[r2 * 20];
            float4 bq = *(const float4*)&Pb[r2 * 20 + 4];
            raw[r2][0] = a.x; raw[r2][1] = a.y; raw[r2][2] = a.z; raw[r2][3] = a.w;
            raw[r2][4] = bq.x; raw[r2][5] = bq.y; raw[r2][6] = bq.z; raw[r2][7] = bq.w;
        }
        float rs[2][5];
        #pragma unroll
        for (int r2 = 0; r2 < 2; ++r2)
            #pragma unroll
            for (int j = 0; j < 5; ++j) rs[r2][j] = px ? raw[r2][j + 1] : raw[r2][j];
        const float* wq = pk3 + (size_t)((c * 4 + q) * 4) * 16;
        #pragma unroll
        for (int t = 0; t < 4; ++t) {
            int wy = t >> 1, wx = t & 1;
            const float* wt = wq + t * 16;
            #pragma unroll
            for (int o = 0; o < 16; ++o) {
                float w = wt[o];
                #pragma unroll
                for (int i = 0; i < 4; ++i)
                    acc[i][o] = fmaf(rs[wy][i + wx], w, acc[i][o]);
            }
        }
    }
    __syncthreads();   // all input-tile reads done; P reusable

    // ---- Phases 2+3 per 8-channel group: stage ReLU'd convt2 output in
    //      zero-haloed [8][30][32] LDS, accumulate conv2 partial sums ----
    const bool active2 = tid < 196;
    int row = active2 ? tid / 7 : 0;
    int tx0b = active2 ? (tid % 7) * 4 : 0;
    const int y = 2 * ty + py;

    float acc2[4][8];
    #pragma unroll
    for (int i = 0; i < 4; ++i)
        #pragma unroll
        for (int o = 0; o < 8; ++o) acc2[i][o] = 0.f;

    #pragma unroll
    for (int g = 0; g < 2; ++g) {
        for (int e = tid; e < 7680; e += 256) P[e] = 0.f;
        __syncthreads();
        if (active) {
            #pragma unroll
            for (int o8 = 0; o8 < 8; ++o8) {
                int o = g * 8 + o8;
                float bo = bt2[o];
                #pragma unroll
                for (int i = 0; i < 4; ++i) {
                    int xt = tx0 + i;
                    if (xt < 14)
                        P[(o8 * 30 + y + 1) * 32 + (2 * xt + px + 1)] = fmaxf(acc[i][o] + bo, 0.f);
                }
            }
        }
        __syncthreads();
        for (int cl = 0; cl < 8; ++cl) {
            const float* Pb = &P[(cl * 30 + row) * 32 + tx0b];
            const float* wb = pk4 + (size_t)(g * 8 + cl) * 72;
            #pragma unroll
            for (int ky = 0; ky < 3; ++ky) {
                float4 a = *(const float4*)&Pb[ky * 32];
                float4 bq = *(const float4*)&Pb[ky * 32 + 4];
                float rowb[8] = {a.x, a.y, a.z, a.w, bq.x, bq.y, bq.z, bq.w};
                #pragma unroll
                for (int kx = 0; kx < 3; ++kx) {
                    const float* wt = wb + (ky * 3 + kx) * 8;
                    #pragma unroll
                    for (int o = 0; o < 8; ++o) {
                        float w = wt[o];
                        #pragma unroll
                        for (int i = 0; i < 4; ++i)
                            acc2[i][o] = fmaf(rowb[i + kx], w, acc2[i][o]);
                    }
                }
            }
        }
        __syncthreads();   // group tile fully consumed before next zero-fill
    }

    // ---- conv3 (8->1, k1) + store ----
    if (active2) {
        const float bias3 = b3[0];
        #pragma unroll
        for (int i = 0; i < 4; ++i) {
            float r = bias3;
            #pragma unroll
            for (int o = 0; o < 8; ++o) r += fmaxf(acc2[i][o] + b2[o], 0.f) * w3[o];
            out[(size_t)b * 784 + row * 28 + tx0b + i] = r;
        }
    }
}

// ---------------------------------------------------------------------------
extern "C" void kernel_launch(void* const* d_in, const int* in_sizes, int n_in,
                              void* d_out, int out_size, void* d_ws, size_t ws_size,
                              hipStream_t stream)
{
    const float* x       = (const float*)d_in[0];
    const float* patch_w = (const float*)d_in[1];
    const float* patch_b = (const float*)d_in[2];
    const float* ln1g    = (const float*)d_in[3];
    const float* ln1b    = (const float*)d_in[4];
    const float* wi      = (const float*)d_in[5];
    const float* bi      = (const float*)d_in[6];
    const float* wo      = (const float*)d_in[7];
    const float* bo      = (const float*)d_in[8];
    const float* ln2g    = (const float*)d_in[9];
    const float* ln2b    = (const float*)d_in[10];
    const float* w1      = (const float*)d_in[11];
    const float* b1      = (const float*)d_in[12];
    const float* w2      = (const float*)d_in[13];
    const float* b2      = (const float*)d_in[14];
    const float* lat_w   = (const float*)d_in[15];
    const float* lat_b   = (const float*)d_in[16];
    const float* memory  = (const float*)d_in[17];
    const float* dec_w   = (const float*)d_in[18];
    const float* dec_b   = (const float*)d_in[19];
    const float* upt1_w  = (const float*)d_in[20];
    const float* upt1_b  = (const float*)d_in[21];
    const float* c1_w    = (const float*)d_in[22];
    const float* c1_b    = (const float*)d_in[23];
    const float* upt2_w  = (const float*)d_in[24];
    const float* upt2_b  = (const float*)d_in[25];
    const float* c2_w    = (const float*)d_in[26];
    const float* c2_b    = (const float*)d_in[27];
    const float* c3_w    = (const float*)d_in[28];
    const float* c3_b    = (const float*)d_in[29];
    float* outp = (float*)d_out;

    float* ws = (float*)d_ws;
    size_t off = 0;
    auto alloc = [&](size_t n) { float* p = ws + off; off += (n + 63) & ~(size_t)63; return p; };
    float* tokens     = alloc((size_t)B_TOT * 1568);
    float* latent     = alloc((size_t)B_TOT * 256);
    float* dots       = alloc((size_t)B_TOT * 4096);
    float* mem_latent = alloc((size_t)B_TOT * 256);
    float* inv_mn     = alloc(4096);
    float* pk2        = alloc(9216);
    float* pk3        = alloc(8192);
    float* pk4        = alloc(1152);
    float* pk5        = alloc(8192);
    float* Wf         = alloc((size_t)6272 * 256);
    float* bf         = alloc(6272);
    float* d1         = alloc((size_t)CHUNK * 6272);
    float* d2         = alloc((size_t)CHUNK * 6272);
    (void)in_sizes; (void)n_in; (void)out_size; (void)ws_size;

    // Weight repack + dec/convt1 algebraic fusion
    k_pack<<<36, 256, 0, stream>>>(c1_w, upt2_w, c2_w, w2, pk2, pk3, pk4, pk5);
    k_fuse<<<6272, 256, 0, stream>>>(upt1_w, upt1_b, dec_w, dec_b, Wf, bf);

    // Encoder (wave-per-sample)
    k_tokens<<<B_TOT / 4, 256, 0, stream>>>(x, patch_w, patch_b, ln1g, ln1b, wi, bi,
                                            wo, bo, ln2g, ln2b, w1, b1, pk5, b2, tokens);
    k_gemm<<<dim3(256 / 64, B_TOT / 128), 256, 0, stream>>>(tokens, lat_w, lat_b, latent,
                                                            B_TOT, 256, 1568, 0);
    k_mnorm<<<4096, 256, 0, stream>>>(memory, inv_mn);
    k_gemm<<<dim3(4096 / 64, B_TOT / 128), 256, 0, stream>>>(latent, memory, nullptr, dots,
                                                             B_TOT, 4096, 256, 0);
    k_memread<<<B_TOT, 256, 0, stream>>>(latent, dots, inv_mn, memory, mem_latent);

    // Decoder, chunked over batch. Fused dec+convt1 GEMM -> d1; conv1 -> d2;
    // fused convt2+conv2+conv3 -> output (no d3 round-trip).
    for (int c = 0; c < B_TOT / CHUNK; ++c) {
        const float* ml = mem_latent + (size_t)c * CHUNK * 256;
        k_gemm<<<dim3(6272 / 64, CHUNK / 128), 256, 0, stream>>>(ml, Wf, bf, d1,
                                                                 CHUNK, 6272, 256, 1);
        k_conv1  <<<CHUNK / 2, 256, 0, stream>>>(d1, pk2, c1_b, d2);
        k_convt23<<<CHUNK, 256, 0, stream>>>(d2, pk3, upt2_b, pk4, c2_b, c3_w, c3_b,
                                             outp + (size_t)c * CHUNK * 784);
    }
}